// Round 1
// baseline (609.946 us; speedup 1.0000x reference)
//
#include <hip/hip_runtime.h>

// RhoLoss: total = sum over pairs (l1<=l2) of w * sum_s d1[s]^T O[s] d2[s]
// S=8, I=32, N=8, K_l = I*(2l+1)*N = {256, 768, 1280, 1792}
// O traffic = 356.5 MB read once. ~178 MB of it is LLC-resident (dirty lines
// left by the harness's input restore); nt loads hit those lines and stream
// the rest from HBM without evicting (R2 lesson).
//
// R3: the static byte-balanced partition is SPEED-unbalanced: LLC-hit waves
// finish ~3x faster than HBM-miss waves -> OccupancyPercent 55%, long tail.
// Fix: dynamic work-stealing over 16384 units (~21.8 KB each). Each wave
// owns one static unit, then steals via a global counter; the steal atomic
// is issued BEFORE processing the current unit so its latency hides under
// the unit's loads. Also: memset dispatch folded into compute_d_kernel.

#define NUM_S 8

typedef float vfloat4 __attribute__((ext_vector_type(4)));

// d layout in g_d: l0 @0 (2048), l1 @2048 (6144), l2 @8192 (10240), l3 @18432 (14336)
__device__ float g_d[32768];
__device__ unsigned g_ctr;   // work-stealing cursor, init to NPW by compute_d

#define NV  16384u   // virtual work units (2x physical waves, ~21.8 KB/unit)
#define NPW 8192u    // physical waves (2048 blocks * 4 waves)

__global__ __launch_bounds__(256) void compute_d_kernel(
    const float* __restrict__ ci0, const float* __restrict__ ct0,
    const float* __restrict__ ci1, const float* __restrict__ ct1,
    const float* __restrict__ ci2, const float* __restrict__ ct2,
    const float* __restrict__ ci3, const float* __restrict__ ct3,
    float* __restrict__ out) {
    const int t = blockIdx.x * 256 + threadIdx.x;  // 0..32767
    if (t == 0) { *out = 0.0f; g_ctr = NPW; }      // d_out poisoned each call
    float v;
    if (t < 2048)       v = ci0[t]         - ct0[t];
    else if (t < 8192)  v = ci1[t - 2048]  - ct1[t - 2048];
    else if (t < 18432) v = ci2[t - 8192]  - ct2[t - 8192];
    else                v = ci3[t - 18432] - ct3[t - 18432];
    g_d[t] = v;
}

// One work unit: contiguous row range [lw*NROWS/NWP, (lw+1)*NROWS/NWP).
// K1,K2,NWP compile-time -> all div/mod become magic multiplies.
template <int K1, int K2, int W, int NWP>
__device__ __forceinline__ float pair_rows(const float* __restrict__ O,
                                           const float* __restrict__ d1,
                                           const float* __restrict__ d2,
                                           int lw, int lane) {
    constexpr int C2q    = K2 / 4;     // float4s per row
    constexpr int ROUNDS = C2q / 64;   // wave-wide float4 loads per row (1,3,5,7)
    constexpr int NROWS  = NUM_S * K1;

    const int r_beg = (int)(((long long)lw * NROWS) / NWP);
    const int r_end = (int)(((long long)(lw + 1) * NROWS) / NWP);

    const vfloat4* __restrict__ O4 = (const vfloat4*)O;

    float ax = 0.f, ay = 0.f, az = 0.f, aw = 0.f;
    for (int t = r_beg; t < r_end; ++t) {
        const int s = t / K1;
        const vfloat4* __restrict__ o = O4 + (size_t)t * C2q + lane;
        const vfloat4* __restrict__ v = (const vfloat4*)(d2 + s * K2) + lane;

        vfloat4 ov[ROUNDS], vv[ROUNDS];
#pragma unroll
        for (int j = 0; j < ROUNDS; ++j)
            ov[j] = __builtin_nontemporal_load(o + j * 64);  // nt: no-allocate
#pragma unroll
        for (int j = 0; j < ROUNDS; ++j) vv[j] = v[j * 64];

        const float dd = d1[t];  // wave-uniform

        float dx = 0.f, dy = 0.f, dz = 0.f, dw = 0.f;
#pragma unroll
        for (int j = 0; j < ROUNDS; ++j) {
            dx = fmaf(ov[j].x, vv[j].x, dx);
            dy = fmaf(ov[j].y, vv[j].y, dy);
            dz = fmaf(ov[j].z, vv[j].z, dz);
            dw = fmaf(ov[j].w, vv[j].w, dw);
        }
        ax = fmaf(dd, dx, ax);
        ay = fmaf(dd, dy, ay);
        az = fmaf(dd, dz, az);
        aw = fmaf(dd, dw, aw);
    }
    return (float)W * ((ax + ay) + (az + aw));
}

// Unit ranges over NV=16384, proportional to per-pair bytes (2x the old
// per-wave split): p00 [0,94) p01 [94,384) p02 [384,866) p03 [866,1540)
// p11 [1540,2408) p12 [2408,3854) p13 [3854,5878) p22 [5878,8288)
// p23 [8288,11662) p33 [11662,16384)
__device__ __forceinline__ float do_unit(
    unsigned v, int lane,
    const float* __restrict__ O00, const float* __restrict__ O01,
    const float* __restrict__ O02, const float* __restrict__ O03,
    const float* __restrict__ O11, const float* __restrict__ O12,
    const float* __restrict__ O13, const float* __restrict__ O22,
    const float* __restrict__ O23, const float* __restrict__ O33) {
    const float* D0 = g_d;
    const float* D1 = g_d + 2048;
    const float* D2 = g_d + 8192;
    const float* D3 = g_d + 18432;

    if      (v <    94u) return pair_rows< 256,  256, 1,   94>(O00, D0, D0, (int)v,           lane);
    else if (v <   384u) return pair_rows< 256,  768, 2,  290>(O01, D0, D1, (int)(v -    94), lane);
    else if (v <   866u) return pair_rows< 256, 1280, 2,  482>(O02, D0, D2, (int)(v -   384), lane);
    else if (v <  1540u) return pair_rows< 256, 1792, 2,  674>(O03, D0, D3, (int)(v -   866), lane);
    else if (v <  2408u) return pair_rows< 768,  768, 1,  868>(O11, D1, D1, (int)(v -  1540), lane);
    else if (v <  3854u) return pair_rows< 768, 1280, 2, 1446>(O12, D1, D2, (int)(v -  2408), lane);
    else if (v <  5878u) return pair_rows< 768, 1792, 2, 2024>(O13, D1, D3, (int)(v -  3854), lane);
    else if (v <  8288u) return pair_rows<1280, 1280, 1, 2410>(O22, D2, D2, (int)(v -  5878), lane);
    else if (v < 11662u) return pair_rows<1280, 1792, 2, 3374>(O23, D2, D3, (int)(v -  8288), lane);
    else                 return pair_rows<1792, 1792, 1, 4722>(O33, D3, D3, (int)(v - 11662), lane);
}

__global__ __launch_bounds__(256) void rho_loss_kernel(
    const float* __restrict__ O00, const float* __restrict__ O01,
    const float* __restrict__ O02, const float* __restrict__ O03,
    const float* __restrict__ O11, const float* __restrict__ O12,
    const float* __restrict__ O13, const float* __restrict__ O22,
    const float* __restrict__ O23, const float* __restrict__ O33,
    float* __restrict__ out) {
    const int lane = threadIdx.x & 63;
    const unsigned pw = blockIdx.x * 4 + (threadIdx.x >> 6);  // 0..8191

    float acc = 0.f;
    unsigned v = pw;  // static first unit, no atomic
    while (v < NV) {
        unsigned nv = 0xffffffffu;
        if (lane == 0) nv = atomicAdd(&g_ctr, 1u);  // issue steal EARLY;
        // latency hides under the ~21.8 KB of loads in do_unit below.

        acc += do_unit(v, lane, O00, O01, O02, O03, O11, O12, O13,
                       O22, O23, O33);

        v = (unsigned)__shfl((int)nv, 0, 64);  // broadcast stolen unit id
    }

    // wave (64-lane) shuffle reduction
    for (int off = 32; off > 0; off >>= 1)
        acc += __shfl_down(acc, off, 64);

    __shared__ float wsum[4];
    const int lwid = threadIdx.x >> 6;
    if (lane == 0) wsum[lwid] = acc;
    __syncthreads();
    if (threadIdx.x == 0) {
        float s = wsum[0] + wsum[1] + wsum[2] + wsum[3];
        atomicAdd(out, s);
    }
}

extern "C" void kernel_launch(void* const* d_in, const int* in_sizes, int n_in,
                              void* d_out, int out_size, void* d_ws, size_t ws_size,
                              hipStream_t stream) {
    (void)in_sizes; (void)n_in; (void)d_ws; (void)ws_size; (void)out_size;

    const float* ci0 = (const float*)d_in[0];
    const float* ct0 = (const float*)d_in[1];
    const float* ci1 = (const float*)d_in[2];
    const float* ct1 = (const float*)d_in[3];
    const float* ci2 = (const float*)d_in[4];
    const float* ct2 = (const float*)d_in[5];
    const float* ci3 = (const float*)d_in[6];
    const float* ct3 = (const float*)d_in[7];
    const float* O00 = (const float*)d_in[8];
    const float* O01 = (const float*)d_in[9];
    const float* O02 = (const float*)d_in[10];
    const float* O03 = (const float*)d_in[11];
    const float* O11 = (const float*)d_in[12];
    const float* O12 = (const float*)d_in[13];
    const float* O13 = (const float*)d_in[14];
    const float* O22 = (const float*)d_in[15];
    const float* O23 = (const float*)d_in[16];
    const float* O33 = (const float*)d_in[17];

    // Stage deltas + zero d_out + init steal counter (one dispatch).
    compute_d_kernel<<<128, 256, 0, stream>>>(ci0, ct0, ci1, ct1,
                                              ci2, ct2, ci3, ct3,
                                              (float*)d_out);

    // 2048 blocks * 4 waves = 8192 physical waves; 8 blocks/CU resident.
    rho_loss_kernel<<<2048, 256, 0, stream>>>(
        O00, O01, O02, O03, O11, O12, O13, O22, O23, O33, (float*)d_out);
}

// Round 2
// 321.158 us; speedup vs baseline: 1.8992x; 1.8992x over previous
//
#include <hip/hip_runtime.h>

// RhoLoss: total = sum over pairs (l1<=l2) of w * sum_s d1[s]^T O[s] d2[s]
// S=8, I=32, N=8, K_l = I*(2l+1)*N = {256, 768, 1280, 1792}
// O traffic = 356.5 MB read once. FETCH=174.6 MB => ~181.9 MB (the
// last-restored suffix: tail of O22 + O23 + O33) is LLC-resident; nt loads
// preserve that residency (R2 lesson).
//
// R3 post-mortem: work-stealing via one global atomic serialized the whole
// kernel on same-address atomic throughput (355us / 16384 ops = 21.7 ns/op).
// R4: balance statically. 32768 byte-balanced units (~10.9 KB); wave w owns
// {w, 16383-w, 16384+w, 32767-w} = 2 units from the HBM-miss half + 2 from
// the LLC-hit half (residency boundary ~ unit 16050). Alternate miss/hit
// per wave, parity-swapped across waves, so both memory systems run
// concurrently and per-wave time is uniform (no tail). Zero atomics.

#define NUM_S 8

typedef float vfloat4 __attribute__((ext_vector_type(4)));

// d layout in g_d: l0 @0 (2048), l1 @2048 (6144), l2 @8192 (10240), l3 @18432 (14336)
__device__ float g_d[32768];

__global__ __launch_bounds__(256) void compute_d_kernel(
    const float* __restrict__ ci0, const float* __restrict__ ct0,
    const float* __restrict__ ci1, const float* __restrict__ ct1,
    const float* __restrict__ ci2, const float* __restrict__ ct2,
    const float* __restrict__ ci3, const float* __restrict__ ct3,
    float* __restrict__ out) {
    const int t = blockIdx.x * 256 + threadIdx.x;  // 0..32767
    if (t == 0) *out = 0.0f;                       // d_out poisoned each call
    float v;
    if (t < 2048)       v = ci0[t]         - ct0[t];
    else if (t < 8192)  v = ci1[t - 2048]  - ct1[t - 2048];
    else if (t < 18432) v = ci2[t - 8192]  - ct2[t - 8192];
    else                v = ci3[t - 18432] - ct3[t - 18432];
    g_d[t] = v;
}

// One work unit: contiguous row range [lw*NROWS/NWP, (lw+1)*NROWS/NWP).
// K1,K2,NWP compile-time -> all div/mod become magic multiplies.
template <int K1, int K2, int W, int NWP>
__device__ __forceinline__ float pair_rows(const float* __restrict__ O,
                                           const float* __restrict__ d1,
                                           const float* __restrict__ d2,
                                           int lw, int lane) {
    constexpr int C2q    = K2 / 4;     // float4s per row
    constexpr int ROUNDS = C2q / 64;   // wave-wide float4 loads per row (1,3,5,7)
    constexpr int NROWS  = NUM_S * K1;

    const int r_beg = (int)(((long long)lw * NROWS) / NWP);
    const int r_end = (int)(((long long)(lw + 1) * NROWS) / NWP);

    const vfloat4* __restrict__ O4 = (const vfloat4*)O;

    float ax = 0.f, ay = 0.f, az = 0.f, aw = 0.f;
    for (int t = r_beg; t < r_end; ++t) {
        const int s = t / K1;
        const vfloat4* __restrict__ o = O4 + (size_t)t * C2q + lane;
        const vfloat4* __restrict__ v = (const vfloat4*)(d2 + s * K2) + lane;

        vfloat4 ov[ROUNDS], vv[ROUNDS];
#pragma unroll
        for (int j = 0; j < ROUNDS; ++j)
            ov[j] = __builtin_nontemporal_load(o + j * 64);  // nt: no-allocate
#pragma unroll
        for (int j = 0; j < ROUNDS; ++j) vv[j] = v[j * 64];

        const float dd = d1[t];  // wave-uniform

        float dx = 0.f, dy = 0.f, dz = 0.f, dw = 0.f;
#pragma unroll
        for (int j = 0; j < ROUNDS; ++j) {
            dx = fmaf(ov[j].x, vv[j].x, dx);
            dy = fmaf(ov[j].y, vv[j].y, dy);
            dz = fmaf(ov[j].z, vv[j].z, dz);
            dw = fmaf(ov[j].w, vv[j].w, dw);
        }
        ax = fmaf(dd, dx, ax);
        ay = fmaf(dd, dy, ay);
        az = fmaf(dd, dz, az);
        aw = fmaf(dd, dw, aw);
    }
    return (float)W * ((ax + ay) + (az + aw));
}

// 32768 units, byte-proportional (~10.9 KB each):
// p00 [0,188) p01 [188,768) p02 [768,1732) p03 [1732,3080) p11 [3080,4816)
// p12 [4816,7708) p13 [7708,11756) p22 [11756,16576) p23 [16576,23324)
// p33 [23324,32768)
__device__ __forceinline__ float do_unit(
    unsigned v, int lane,
    const float* __restrict__ O00, const float* __restrict__ O01,
    const float* __restrict__ O02, const float* __restrict__ O03,
    const float* __restrict__ O11, const float* __restrict__ O12,
    const float* __restrict__ O13, const float* __restrict__ O22,
    const float* __restrict__ O23, const float* __restrict__ O33) {
    const float* D0 = g_d;
    const float* D1 = g_d + 2048;
    const float* D2 = g_d + 8192;
    const float* D3 = g_d + 18432;

    if      (v <   188u) return pair_rows< 256,  256, 1,  188>(O00, D0, D0, (int)v,            lane);
    else if (v <   768u) return pair_rows< 256,  768, 2,  580>(O01, D0, D1, (int)(v -   188), lane);
    else if (v <  1732u) return pair_rows< 256, 1280, 2,  964>(O02, D0, D2, (int)(v -   768), lane);
    else if (v <  3080u) return pair_rows< 256, 1792, 2, 1348>(O03, D0, D3, (int)(v -  1732), lane);
    else if (v <  4816u) return pair_rows< 768,  768, 1, 1736>(O11, D1, D1, (int)(v -  3080), lane);
    else if (v <  7708u) return pair_rows< 768, 1280, 2, 2892>(O12, D1, D2, (int)(v -  4816), lane);
    else if (v < 11756u) return pair_rows< 768, 1792, 2, 4048>(O13, D1, D3, (int)(v -  7708), lane);
    else if (v < 16576u) return pair_rows<1280, 1280, 1, 4820>(O22, D2, D2, (int)(v - 11756), lane);
    else if (v < 23324u) return pair_rows<1280, 1792, 2, 6748>(O23, D2, D3, (int)(v - 16576), lane);
    else                 return pair_rows<1792, 1792, 1, 9444>(O33, D3, D3, (int)(v - 23324), lane);
}

__global__ __launch_bounds__(256) void rho_loss_kernel(
    const float* __restrict__ O00, const float* __restrict__ O01,
    const float* __restrict__ O02, const float* __restrict__ O03,
    const float* __restrict__ O11, const float* __restrict__ O12,
    const float* __restrict__ O13, const float* __restrict__ O22,
    const float* __restrict__ O23, const float* __restrict__ O33,
    float* __restrict__ out) {
    const int lane = threadIdx.x & 63;
    const unsigned pw = blockIdx.x * 4 + (threadIdx.x >> 6);  // 0..8191

    // Units: a=pw (miss half), b=16383-pw (miss half), c=16384+pw (hit half),
    // d=32767-pw (hit half). Alternate miss/hit; parity-swap start so half
    // the machine is on HBM and half on LLC at any instant. Wave-uniform
    // branch (pw uniform within a wave).
    float acc = 0.f;
    if ((pw & 1u) == 0u) {
        acc += do_unit(pw,          lane, O00, O01, O02, O03, O11, O12, O13, O22, O23, O33);
        acc += do_unit(16384u + pw, lane, O00, O01, O02, O03, O11, O12, O13, O22, O23, O33);
        acc += do_unit(16383u - pw, lane, O00, O01, O02, O03, O11, O12, O13, O22, O23, O33);
        acc += do_unit(32767u - pw, lane, O00, O01, O02, O03, O11, O12, O13, O22, O23, O33);
    } else {
        acc += do_unit(16384u + pw, lane, O00, O01, O02, O03, O11, O12, O13, O22, O23, O33);
        acc += do_unit(pw,          lane, O00, O01, O02, O03, O11, O12, O13, O22, O23, O33);
        acc += do_unit(32767u - pw, lane, O00, O01, O02, O03, O11, O12, O13, O22, O23, O33);
        acc += do_unit(16383u - pw, lane, O00, O01, O02, O03, O11, O12, O13, O22, O23, O33);
    }

    // wave (64-lane) shuffle reduction
    for (int off = 32; off > 0; off >>= 1)
        acc += __shfl_down(acc, off, 64);

    __shared__ float wsum[4];
    const int lwid = threadIdx.x >> 6;
    if (lane == 0) wsum[lwid] = acc;
    __syncthreads();
    if (threadIdx.x == 0) {
        float s = wsum[0] + wsum[1] + wsum[2] + wsum[3];
        atomicAdd(out, s);
    }
}

extern "C" void kernel_launch(void* const* d_in, const int* in_sizes, int n_in,
                              void* d_out, int out_size, void* d_ws, size_t ws_size,
                              hipStream_t stream) {
    (void)in_sizes; (void)n_in; (void)d_ws; (void)ws_size; (void)out_size;

    const float* ci0 = (const float*)d_in[0];
    const float* ct0 = (const float*)d_in[1];
    const float* ci1 = (const float*)d_in[2];
    const float* ct1 = (const float*)d_in[3];
    const float* ci2 = (const float*)d_in[4];
    const float* ct2 = (const float*)d_in[5];
    const float* ci3 = (const float*)d_in[6];
    const float* ct3 = (const float*)d_in[7];
    const float* O00 = (const float*)d_in[8];
    const float* O01 = (const float*)d_in[9];
    const float* O02 = (const float*)d_in[10];
    const float* O03 = (const float*)d_in[11];
    const float* O11 = (const float*)d_in[12];
    const float* O12 = (const float*)d_in[13];
    const float* O13 = (const float*)d_in[14];
    const float* O22 = (const float*)d_in[15];
    const float* O23 = (const float*)d_in[16];
    const float* O33 = (const float*)d_in[17];

    // Stage deltas + zero d_out (one dispatch, no separate memset).
    compute_d_kernel<<<128, 256, 0, stream>>>(ci0, ct0, ci1, ct1,
                                              ci2, ct2, ci3, ct3,
                                              (float*)d_out);

    // 2048 blocks * 4 waves = 8192 physical waves; 8 blocks/CU resident.
    rho_loss_kernel<<<2048, 256, 0, stream>>>(
        O00, O01, O02, O03, O11, O12, O13, O22, O23, O33, (float*)d_out);
}

// Round 3
// 318.551 us; speedup vs baseline: 1.9147x; 1.0082x over previous
//
#include <hip/hip_runtime.h>

// RhoLoss: total = sum over pairs (l1<=l2) of w * sum_s d1[s]^T O[s] d2[s]
// S=8, I=32, N=8, K_l = I*(2l+1)*N = {256, 768, 1280, 1792}
// O traffic = 356.5 MB streamed once.
//
// History: R2 (static byte-balanced contiguous partition + nt loads) = 65.4us.
// R3 (global-atomic work stealing) = 355us: same-address atomic throughput
// (21.7 ns/op) serialized the grid. R4 (static hit/miss interleave) = 68.3us:
// NULL -> no positional LLC/HBM speed split exists; FETCH_SIZE ~= O/2 exactly
// is a counting artifact, the whole 356.5 MB streams uniformly at 5.45 TB/s
// (87% of the 6.29 TB/s copy ceiling).
//
// R5: R2 structure + two per-wave issue-density fixes:
//  (a) d2 row (vv) hoisted out of the row loop -- it only changes when
//      s = t/K1 changes, which for most waves is never. The old code
//      re-loaded the same 7KB from L2 every row (half of all loop VMEM).
//  (b) #pragma unroll 2 on the row loop: two independent O-rows in flight.

#define NUM_S 8

typedef float vfloat4 __attribute__((ext_vector_type(4)));

// d layout in g_d: l0 @0 (2048), l1 @2048 (6144), l2 @8192 (10240), l3 @18432 (14336)
__device__ float g_d[32768];

__global__ __launch_bounds__(256) void compute_d_kernel(
    const float* __restrict__ ci0, const float* __restrict__ ct0,
    const float* __restrict__ ci1, const float* __restrict__ ct1,
    const float* __restrict__ ci2, const float* __restrict__ ct2,
    const float* __restrict__ ci3, const float* __restrict__ ct3,
    float* __restrict__ out) {
    const int t = blockIdx.x * 256 + threadIdx.x;  // 0..32767
    if (t == 0) *out = 0.0f;                       // d_out poisoned each call
    float v;
    if (t < 2048)       v = ci0[t]         - ct0[t];
    else if (t < 8192)  v = ci1[t - 2048]  - ct1[t - 2048];
    else if (t < 18432) v = ci2[t - 8192]  - ct2[t - 8192];
    else                v = ci3[t - 18432] - ct3[t - 18432];
    g_d[t] = v;
}

// One pair, one wave: contiguous row range [lw*NROWS/NWP, (lw+1)*NROWS/NWP).
// K1,K2,NWP compile-time -> all div/mod become magic multiplies.
template <int K1, int K2, int W, int NWP>
__device__ __forceinline__ float pair_rows(const float* __restrict__ O,
                                           const float* __restrict__ d1,
                                           const float* __restrict__ d2,
                                           int lw, int lane) {
    constexpr int C2q    = K2 / 4;     // float4s per row
    constexpr int ROUNDS = C2q / 64;   // wave-wide float4 loads per row (1,3,5,7)
    constexpr int NROWS  = NUM_S * K1;

    const int r_beg = (int)(((long long)lw * NROWS) / NWP);
    const int r_end = (int)(((long long)(lw + 1) * NROWS) / NWP);

    const vfloat4* __restrict__ O4 = (const vfloat4*)O;

    float ax = 0.f, ay = 0.f, az = 0.f, aw = 0.f;

    int t = r_beg;
    while (t < r_end) {
        const int s        = t / K1;                 // structure index
        const int seg_full = (s + 1) * K1;           // next s boundary
        const int seg_end  = seg_full < r_end ? seg_full : r_end;

        // d2 row for this structure: loaded ONCE per segment (L2-hot, tiny)
        const vfloat4* __restrict__ v = (const vfloat4*)(d2 + s * K2) + lane;
        vfloat4 vv[ROUNDS];
#pragma unroll
        for (int j = 0; j < ROUNDS; ++j) vv[j] = v[j * 64];

        // inner loop: pure nt O-stream + FMA; 2 rows in flight
#pragma unroll 2
        for (int u = t; u < seg_end; ++u) {
            const vfloat4* __restrict__ o = O4 + (size_t)u * C2q + lane;
            vfloat4 ov[ROUNDS];
#pragma unroll
            for (int j = 0; j < ROUNDS; ++j)
                ov[j] = __builtin_nontemporal_load(o + j * 64);  // nt: no-allocate

            const float dd = d1[u];  // wave-uniform -> s_load

            float dx = 0.f, dy = 0.f, dz = 0.f, dw = 0.f;
#pragma unroll
            for (int j = 0; j < ROUNDS; ++j) {
                dx = fmaf(ov[j].x, vv[j].x, dx);
                dy = fmaf(ov[j].y, vv[j].y, dy);
                dz = fmaf(ov[j].z, vv[j].z, dz);
                dw = fmaf(ov[j].w, vv[j].w, dw);
            }
            ax = fmaf(dd, dx, ax);
            ay = fmaf(dd, dy, ay);
            az = fmaf(dd, dz, az);
            aw = fmaf(dd, dw, aw);
        }
        t = seg_end;
    }
    return (float)W * ((ax + ay) + (az + aw));
}

// Wave-range partition over 8192 waves, proportional to per-pair bytes
// (each wave ~43.5 KB contiguous) -- identical to R2 (proven best).
__global__ __launch_bounds__(256) void rho_loss_kernel(
    const float* __restrict__ O00, const float* __restrict__ O01,
    const float* __restrict__ O02, const float* __restrict__ O03,
    const float* __restrict__ O11, const float* __restrict__ O12,
    const float* __restrict__ O13, const float* __restrict__ O22,
    const float* __restrict__ O23, const float* __restrict__ O33,
    float* __restrict__ out) {
    const int lane = threadIdx.x & 63;
    const int wid  = blockIdx.x * 4 + (threadIdx.x >> 6);  // 0..8191

    const float* D0 = g_d;
    const float* D1 = g_d + 2048;
    const float* D2 = g_d + 8192;
    const float* D3 = g_d + 18432;

    float acc;
    // ranges: p00 [0,47) p01 [47,192) p02 [192,433) p03 [433,770)
    //         p11 [770,1204) p12 [1204,1927) p13 [1927,2939)
    //         p22 [2939,4144) p23 [4144,5831) p33 [5831,8192)
    if      (wid <   47) acc = pair_rows< 256,  256, 1,   47>(O00, D0, D0, wid,        lane);
    else if (wid <  192) acc = pair_rows< 256,  768, 2,  145>(O01, D0, D1, wid -   47, lane);
    else if (wid <  433) acc = pair_rows< 256, 1280, 2,  241>(O02, D0, D2, wid -  192, lane);
    else if (wid <  770) acc = pair_rows< 256, 1792, 2,  337>(O03, D0, D3, wid -  433, lane);
    else if (wid < 1204) acc = pair_rows< 768,  768, 1,  434>(O11, D1, D1, wid -  770, lane);
    else if (wid < 1927) acc = pair_rows< 768, 1280, 2,  723>(O12, D1, D2, wid - 1204, lane);
    else if (wid < 2939) acc = pair_rows< 768, 1792, 2, 1012>(O13, D1, D3, wid - 1927, lane);
    else if (wid < 4144) acc = pair_rows<1280, 1280, 1, 1205>(O22, D2, D2, wid - 2939, lane);
    else if (wid < 5831) acc = pair_rows<1280, 1792, 2, 1687>(O23, D2, D3, wid - 4144, lane);
    else                 acc = pair_rows<1792, 1792, 1, 2361>(O33, D3, D3, wid - 5831, lane);

    // wave (64-lane) shuffle reduction
    for (int off = 32; off > 0; off >>= 1)
        acc += __shfl_down(acc, off, 64);

    __shared__ float wsum[4];
    const int lwid = threadIdx.x >> 6;
    if (lane == 0) wsum[lwid] = acc;
    __syncthreads();
    if (threadIdx.x == 0) {
        float s = wsum[0] + wsum[1] + wsum[2] + wsum[3];
        atomicAdd(out, s);
    }
}

extern "C" void kernel_launch(void* const* d_in, const int* in_sizes, int n_in,
                              void* d_out, int out_size, void* d_ws, size_t ws_size,
                              hipStream_t stream) {
    (void)in_sizes; (void)n_in; (void)d_ws; (void)ws_size; (void)out_size;

    const float* ci0 = (const float*)d_in[0];
    const float* ct0 = (const float*)d_in[1];
    const float* ci1 = (const float*)d_in[2];
    const float* ct1 = (const float*)d_in[3];
    const float* ci2 = (const float*)d_in[4];
    const float* ct2 = (const float*)d_in[5];
    const float* ci3 = (const float*)d_in[6];
    const float* ct3 = (const float*)d_in[7];
    const float* O00 = (const float*)d_in[8];
    const float* O01 = (const float*)d_in[9];
    const float* O02 = (const float*)d_in[10];
    const float* O03 = (const float*)d_in[11];
    const float* O11 = (const float*)d_in[12];
    const float* O12 = (const float*)d_in[13];
    const float* O13 = (const float*)d_in[14];
    const float* O22 = (const float*)d_in[15];
    const float* O23 = (const float*)d_in[16];
    const float* O33 = (const float*)d_in[17];

    // Stage deltas + zero d_out (one dispatch, no separate memset).
    compute_d_kernel<<<128, 256, 0, stream>>>(ci0, ct0, ci1, ct1,
                                              ci2, ct2, ci3, ct3,
                                              (float*)d_out);

    // 2048 blocks * 4 waves = 8192 waves; 8 blocks/CU resident.
    rho_loss_kernel<<<2048, 256, 0, stream>>>(
        O00, O01, O02, O03, O11, O12, O13, O22, O23, O33, (float*)d_out);
}